// Round 4
// baseline (7714.462 us; speedup 1.0000x reference)
//
#include <hip/hip_runtime.h>

#define T_LEN 256
#define B_SZ  64
#define H_SZ  1024
#define G4H   4096
#define HB    (B_SZ * H_SZ)              // 65536
#define NBLK  256                        // compute WGs ONLY

typedef __attribute__((ext_vector_type(8))) short short8;
typedef __attribute__((ext_vector_type(4))) float float4_;
typedef __attribute__((ext_vector_type(4))) unsigned int uint4_;
typedef __attribute__((ext_vector_type(8))) unsigned int uint8_;

__device__ __forceinline__ unsigned short bf16_rne(float x) {
  unsigned u = __builtin_bit_cast(unsigned, x);
  unsigned r = u + 0x7FFFu + ((u >> 16) & 1u);
  return (unsigned short)(r >> 16);
}
__device__ __forceinline__ float bf16_to_f32(unsigned short s) {
  unsigned u = ((unsigned)s) << 16;
  return __builtin_bit_cast(float, u);
}

// ---------- prep: x fp32 -> packed split-bf16 (hi | lo<<16) dwords ----------
__global__ __launch_bounds__(256)
void pack_x(const float* __restrict__ src, unsigned* __restrict__ dst) {
  const size_t i = ((size_t)blockIdx.x * 256 + threadIdx.x) * 4;
  float4_ v = *(const float4_*)(src + i);
  uint4_ o;
  #pragma unroll
  for (int j = 0; j < 4; ++j) {
    const unsigned short h = bf16_rne(v[j]);
    const unsigned short l = bf16_rne(v[j] - bf16_to_f32(h));
    o[j] = (unsigned)h | ((unsigned)l << 16);
  }
  *(uint4_*)(dst + i) = o;
}

// ---------- prep: h0 -> ring slot 7 (t = -1) + zero sync state ----------
__global__ __launch_bounds__(256)
void init_h(const float* __restrict__ h0, unsigned* __restrict__ ringp,
            unsigned* __restrict__ bar) {
  if (blockIdx.x == 0) {
    #pragma unroll
    for (int j = 0; j < 4; ++j) bar[threadIdx.x * 4 + j] = 0u;
  }
  const int e0 = (blockIdx.x * 256 + threadIdx.x) * 4;
  #pragma unroll
  for (int j = 0; j < 4; ++j) {
    const int e = e0 + j;                 // [2][B][H] = 131072 elems
    const int l = e >> 16;
    const int rem = e & (HB - 1);
    const float v = h0[e];
    const unsigned hh = bf16_rne(v);
    const unsigned ll = bf16_rne(v - bf16_to_f32((unsigned short)hh));
    ringp[(size_t)(l * 8 + 7) * HB + rem] = hh | (ll << 16);
  }
}

__device__ __forceinline__ void poll_ge(const unsigned* p, unsigned v) {
  while (__hip_atomic_load(p, __ATOMIC_RELAXED, __HIP_MEMORY_SCOPE_AGENT) < v)
    __builtin_amdgcn_s_sleep(1);
}

// leader wave: poll all 128 own-layer slots (64 lanes x 2), publish go x4
__device__ __forceinline__ void leader_wait_publish(const unsigned* slots,
                                                    unsigned* gow,
                                                    unsigned v, int lane) {
  for (;;) {
    const unsigned a = __hip_atomic_load(slots + lane, __ATOMIC_RELAXED,
                                         __HIP_MEMORY_SCOPE_AGENT);
    const unsigned b = __hip_atomic_load(slots + lane + 64, __ATOMIC_RELAXED,
                                         __HIP_MEMORY_SCOPE_AGENT);
    if (__all((int)(a >= v && b >= v))) break;
    __builtin_amdgcn_s_sleep(1);
  }
  if (lane < 4)
    __hip_atomic_store(gow + lane * 32, v, __ATOMIC_RELAXED,
                       __HIP_MEMORY_SCOPE_AGENT);
}

// 32 B coherent row fragment: 4x agent-scope atomic b64 loads (bypass L1/L2,
// read at the coherence point -> no acquire fence / L2 invalidate needed).
__device__ __forceinline__ void load_row32_coh(uint8_& u, const unsigned* p) {
  const unsigned long long* q = (const unsigned long long*)p;
  #pragma unroll
  for (int i = 0; i < 4; ++i) {
    const unsigned long long d =
        __hip_atomic_load(q + i, __ATOMIC_RELAXED, __HIP_MEMORY_SCOPE_AGENT);
    u[2 * i]     = (unsigned)d;
    u[2 * i + 1] = (unsigned)(d >> 32);
  }
}

__device__ __forceinline__ void unpack_mfma(float4_ (&acc)[4][2],
                                            const uint8_& u,
                                            const short8 (&wp)[2][2][4],
                                            const int m, const int kb) {
  uint4_ h4, l4;
  #pragma unroll
  for (int r = 0; r < 4; ++r) {
    h4[r] = __builtin_amdgcn_perm(u[2 * r + 1], u[2 * r], 0x05040100u);
    l4[r] = __builtin_amdgcn_perm(u[2 * r + 1], u[2 * r], 0x07060302u);
  }
  const short8 hi = __builtin_bit_cast(short8, h4);
  const short8 lo = __builtin_bit_cast(short8, l4);
  #pragma unroll
  for (int nt = 0; nt < 2; ++nt) {
    acc[m][nt] = __builtin_amdgcn_mfma_f32_16x16x32_bf16(hi, wp[0][nt][kb], acc[m][nt], 0, 0, 0);
    acc[m][nt] = __builtin_amdgcn_mfma_f32_16x16x32_bf16(lo, wp[0][nt][kb], acc[m][nt], 0, 0, 0);
    acc[m][nt] = __builtin_amdgcn_mfma_f32_16x16x32_bf16(hi, wp[1][nt][kb], acc[m][nt], 0, 0, 0);
  }
}

// ring-sourced half-GEMM: coherent loads, 1-kb lookahead double buffer
__device__ __forceinline__ void accum_ring(float4_ (&acc)[4][2],
                                           const unsigned* src,
                                           const short8 (&wp)[2][2][4],
                                           const int nn, const int quad,
                                           const int wave) {
  uint8_ ua[4], ub[4];
  const int kbase = wave * 128 + quad * 8;
  #pragma unroll
  for (int m = 0; m < 4; ++m)
    load_row32_coh(ua[m], src + (size_t)(m * 16 + nn) * H_SZ + kbase);
  #pragma unroll
  for (int kb = 0; kb < 4; ++kb) {
    uint8_* cur = (kb & 1) ? ub : ua;
    uint8_* nxt = (kb & 1) ? ua : ub;
    if (kb < 3) {
      #pragma unroll
      for (int m = 0; m < 4; ++m)
        load_row32_coh(nxt[m], src + (size_t)(m * 16 + nn) * H_SZ +
                               kbase + (kb + 1) * 32);
    }
    #pragma unroll
    for (int m = 0; m < 4; ++m)
      unpack_mfma(acc, cur[m], wp, m, kb);
  }
}

// plain-cached half-GEMM (read-only xpack: L2 stays warm, no fences anywhere)
__device__ __forceinline__ void accum_plain(float4_ (&acc)[4][2],
                                            const unsigned* src,
                                            const short8 (&wp)[2][2][4],
                                            const int nn, const int quad,
                                            const int wave) {
  #pragma unroll
  for (int kb = 0; kb < 4; ++kb) {
    const int k0 = wave * 128 + kb * 32 + quad * 8;
    #pragma unroll
    for (int m = 0; m < 4; ++m) {
      const uint8_ u = *(const uint8_*)(src + (size_t)(m * 16 + nn) * H_SZ + k0);
      unpack_mfma(acc, u, wp, m, kb);
    }
  }
}

// ---------- persistent LSTM: per-layer decoupled pipelines, fence-free ------
// Layer l runs its own t=0..255, synced among its 128 WGs via RMW-free slot
// stores + leader WG (cb==0) publishing go. NO acquire fences: ring reads go
// through agent-scope atomic loads (coherence point), read-only data stays
// cached in L2. Cross-layer gates:
//   layer1 prologue/shadow (reads h0(t)) : go0 >= t+1 / t+2
//   layer0 ring-slot reuse               : go1 >= t-7   (8-deep ring)
__global__ __launch_bounds__(512, 1)
void lstm_persist(const unsigned* __restrict__ xp,     // packed x [T][B][H]
                  const float* __restrict__ c0_in,
                  const float* __restrict__ Wih,       // fp32 [L][4H][H]
                  const float* __restrict__ Whh,
                  const float* __restrict__ bih,
                  const float* __restrict__ bhh,
                  unsigned* __restrict__ ringp,        // [L][8 slots][B][H] packed
                  float* __restrict__ out,
                  unsigned* __restrict__ bar)
{
  const int wg   = blockIdx.x;
  const int tid  = threadIdx.x;
  const int lane = tid & 63;
  const int wave = tid >> 6;

  const int layer = wg >> 7;
  const int cb    = wg & 127;
  const int nn    = lane & 15;
  const int quad  = lane >> 4;

  __shared__ float lds[8][64][36];

  int growA[2];
  #pragma unroll
  for (int nt = 0; nt < 2; ++nt) {
    const int q = nt * 2 + (nn >> 3);
    growA[nt] = q * H_SZ + cb * 8 + (nn & 7);
  }

  // ---- one-time: fp32 weights -> split-bf16 register fragments
  short8 wreg[2][2][2][4];  // [mat(ih,hh)][plane(hi,lo)][ntile][kb]
  #pragma unroll
  for (int mat = 0; mat < 2; ++mat) {
    const float* wsrc = mat ? Whh : Wih;
    #pragma unroll
    for (int nt = 0; nt < 2; ++nt)
      #pragma unroll
      for (int kb = 0; kb < 4; ++kb) {
        const float* p = wsrc + ((size_t)layer * G4H + growA[nt]) * H_SZ +
                         wave * 128 + kb * 32 + quad * 8;
        short8 hi, lo;
        #pragma unroll
        for (int j = 0; j < 8; ++j) {
          const float v = p[j];
          const unsigned short h = bf16_rne(v);
          hi[j] = (short)h;
          lo[j] = (short)bf16_rne(v - bf16_to_f32(h));
        }
        wreg[mat][0][nt][kb] = hi;
        wreg[mat][1][nt][kb] = lo;
      }
  }

  // ---- reduce-phase mapping + bias preload
  const int rb    = tid >> 3;
  const int rhc   = tid & 7;
  const int rhcol = cb * 8 + rhc;
  float4_ bias4;
  #pragma unroll
  for (int q = 0; q < 4; ++q)
    bias4[q] = bih[layer * G4H + q * H_SZ + rhcol] +
               bhh[layer * G4H + q * H_SZ + rhcol];

  unsigned*       slotp     = bar + layer * 128 + cb;
  const unsigned* slots_own = bar + layer * 128;
  unsigned*       go_own_w  = bar + 256 + layer * 128;
  const unsigned* go_own    = bar + 256 + layer * 128 + ((cb >> 5) & 3) * 32;
  const unsigned* go_oth    = bar + 256 + (1 - layer) * 128 + ((cb >> 5) & 3) * 32;

  const unsigned* ring_own = ringp + (size_t)layer * 8 * HB;
  const unsigned* ring_l0  = ringp;

  float creg = 0.f;
  float4_ acc[4][2];
  #pragma unroll
  for (int m = 0; m < 4; ++m)
    #pragma unroll
    for (int nt = 0; nt < 2; ++nt)
      acc[m][nt] = float4_{0.f, 0.f, 0.f, 0.f};

  // ---- prologue: x-side for t=0
  if (layer == 0) {
    accum_plain(acc, xp, wreg[0], nn, quad, wave);
  } else {
    if (tid == 0) poll_ge(go_oth, 1u);                 // h0(0) published
    __syncthreads();
    accum_ring(acc, ring_l0 /*slot 0*/, wreg[0], nn, quad, wave);
  }

  #pragma unroll 1
  for (int t = 0; t < T_LEN; ++t) {
    // ---- wait: own-layer h(t-1) ready (+ layer0 ring-reuse gate)
    if (t > 0) {
      if (cb == 0) {
        if (wave == 0)
          leader_wait_publish(slots_own, go_own_w, (unsigned)t, lane);
      } else if (tid == 0) {
        poll_ge(go_own, (unsigned)t);
      }
      if (tid == 0 && layer == 0 && t >= 8)
        poll_ge(go_oth, (unsigned)(t - 7));
      __syncthreads();
    }

    // ---- recurrent half: h_own(t-1), ring slot (t-1)&7, coherent loads
    accum_ring(acc, ring_own + (size_t)((t + 7) & 7) * HB,
               wreg[1], nn, quad, wave);

    // ---- partials -> LDS, gate-permuted col = hcol*4 + gate
    #pragma unroll
    for (int m = 0; m < 4; ++m)
      #pragma unroll
      for (int nt = 0; nt < 2; ++nt)
        #pragma unroll
        for (int r = 0; r < 4; ++r)
          lds[wave][m * 16 + quad * 4 + r]
             [((nn & 7) << 2) + nt * 2 + (nn >> 3)] = acc[m][nt][r];
    __syncthreads();

    // ---- reduce over 8 K-waves + fused elementwise
    float4_ g4 = bias4;
    #pragma unroll
    for (int w = 0; w < 8; ++w)
      g4 += *(const float4_*)&lds[w][rb][rhc << 2];
    const float cprev = (t == 0)
        ? c0_in[(size_t)layer * HB + (size_t)rb * H_SZ + rhcol]
        : creg;
    const float ig = 1.f / (1.f + __expf(-g4[0]));
    const float fg = 1.f / (1.f + __expf(-g4[1]));
    const float gg = tanhf(g4[2]);
    const float og = 1.f / (1.f + __expf(-g4[3]));
    const float cn = fg * cprev + ig * gg;
    const float hn = og * tanhf(cn);
    creg = cn;
    const size_t ridx = (size_t)(layer * 8 + (t & 7)) * HB +
                        (size_t)rb * H_SZ + rhcol;
    const unsigned hh = bf16_rne(hn);
    const unsigned ll = bf16_rne(hn - bf16_to_f32((unsigned short)hh));
    __hip_atomic_store(&ringp[ridx], hh | (ll << 16),
                       __ATOMIC_RELAXED, __HIP_MEMORY_SCOPE_AGENT);
    if (layer == 1 && t == T_LEN - 1)
      out[(size_t)rb * H_SZ + rhcol] = hn;

    // ---- arrive: drain ring stores, then slot store (release ordering)
    __syncthreads();
    if (tid == 0) {
      __builtin_amdgcn_s_waitcnt(0);
      __hip_atomic_store(slotp, (unsigned)(t + 1),
                         __ATOMIC_RELAXED, __HIP_MEMORY_SCOPE_AGENT);
    }

    // ---- shadow: x-side for t+1 (overlaps own-barrier propagation)
    if (t < T_LEN - 1) {
      if (layer == 1) {
        if (tid == 0) poll_ge(go_oth, (unsigned)(t + 2));  // h0(t+1) ready
        __syncthreads();
      }
      #pragma unroll
      for (int m = 0; m < 4; ++m)
        #pragma unroll
        for (int nt = 0; nt < 2; ++nt)
          acc[m][nt] = float4_{0.f, 0.f, 0.f, 0.f};
      if (layer == 0)
        accum_plain(acc, xp + (size_t)(t + 1) * HB, wreg[0], nn, quad, wave);
      else
        accum_ring(acc, ring_l0 + (size_t)((t + 1) & 7) * HB,
                   wreg[0], nn, quad, wave);
    }
  }

  // ---- epilogue: layer-0 leader publishes go0=256 (layer1's last shadow gate)
  if (layer == 0 && cb == 0 && wave == 0)
    leader_wait_publish(slots_own, go_own_w, (unsigned)T_LEN, lane);
}

extern "C" void kernel_launch(void* const* d_in, const int* in_sizes, int n_in,
                              void* d_out, int out_size, void* d_ws, size_t ws_size,
                              hipStream_t stream) {
  (void)in_sizes; (void)n_in; (void)out_size; (void)ws_size;
  const float* x   = (const float*)d_in[0];
  const float* h0  = (const float*)d_in[1];
  const float* c0  = (const float*)d_in[2];
  const float* Wih = (const float*)d_in[3];
  const float* Whh = (const float*)d_in[4];
  const float* bih = (const float*)d_in[5];
  const float* bhh = (const float*)d_in[6];
  float* out = (float*)d_out;

  // workspace (~68.3 MB): xpack 64 MB | ring 4 MB | bar 4 KB
  char* w = (char*)d_ws;
  unsigned* xpack = (unsigned*)w;                                   // T*HB uints
  unsigned* ringp = (unsigned*)(w + (size_t)T_LEN * HB * 4);        // 2L*8slots*HB
  unsigned* bar   = (unsigned*)(w + (size_t)T_LEN * HB * 4
                                  + (size_t)16 * HB * 4);           // 4 KB

  pack_x<<<(T_LEN * HB) / 4 / 256, 256, 0, stream>>>(x, xpack);
  init_h<<<2 * HB / 4 / 256, 256, 0, stream>>>(h0, ringp, bar);
  lstm_persist<<<NBLK, 512, 0, stream>>>(xpack, c0, Wih, Whh, bih, bhh,
                                         ringp, out, bar);
}

// Round 5
// 4963.654 us; speedup vs baseline: 1.5542x; 1.5542x over previous
//
#include <hip/hip_runtime.h>

#define T_LEN 256
#define B_SZ  64
#define H_SZ  1024
#define G4H   4096
#define HB    (B_SZ * H_SZ)              // 65536
#define NBLK  256                        // compute WGs ONLY
#define RING_SLOTS (T_LEN + 1)           // slot t = h(t); slot T_LEN = h(-1)

typedef __attribute__((ext_vector_type(8))) short short8;
typedef __attribute__((ext_vector_type(4))) float float4_;
typedef __attribute__((ext_vector_type(4))) unsigned int uint4_;
typedef __attribute__((ext_vector_type(8))) unsigned int uint8_;

__device__ __forceinline__ unsigned short bf16_rne(float x) {
  unsigned u = __builtin_bit_cast(unsigned, x);
  unsigned r = u + 0x7FFFu + ((u >> 16) & 1u);
  return (unsigned short)(r >> 16);
}
__device__ __forceinline__ float bf16_to_f32(unsigned short s) {
  unsigned u = ((unsigned)s) << 16;
  return __builtin_bit_cast(float, u);
}

// ---------- prep: h0 -> ring slot T_LEN (t = -1) + zero sync state ----------
__global__ __launch_bounds__(256)
void init_h(const float* __restrict__ h0, unsigned* __restrict__ ringp,
            unsigned* __restrict__ bar) {
  if (blockIdx.x == 0) {
    #pragma unroll
    for (int j = 0; j < 4; ++j) bar[threadIdx.x * 4 + j] = 0u;
  }
  const int e0 = (blockIdx.x * 256 + threadIdx.x) * 4;
  #pragma unroll
  for (int j = 0; j < 4; ++j) {
    const int e = e0 + j;                 // [2][B][H] = 131072 elems
    const int l = e >> 16;
    const int rem = e & (HB - 1);
    const float v = h0[e];
    const unsigned hh = bf16_rne(v);
    const unsigned ll = bf16_rne(v - bf16_to_f32((unsigned short)hh));
    ringp[((size_t)l * RING_SLOTS + T_LEN) * HB + rem] = hh | (ll << 16);
  }
}

__device__ __forceinline__ void poll_ge(const unsigned* p, unsigned v) {
  while (__hip_atomic_load(p, __ATOMIC_RELAXED, __HIP_MEMORY_SCOPE_AGENT) < v)
    __builtin_amdgcn_s_sleep(1);
}

// leader wave: poll all 128 own-layer slots (64 lanes x 2), publish go x4
__device__ __forceinline__ void leader_wait_publish(const unsigned* slots,
                                                    unsigned* gow,
                                                    unsigned v, int lane) {
  for (;;) {
    const unsigned a = __hip_atomic_load(slots + lane, __ATOMIC_RELAXED,
                                         __HIP_MEMORY_SCOPE_AGENT);
    const unsigned b = __hip_atomic_load(slots + lane + 64, __ATOMIC_RELAXED,
                                         __HIP_MEMORY_SCOPE_AGENT);
    if (__all((int)(a >= v && b >= v))) break;
    __builtin_amdgcn_s_sleep(1);
  }
  if (lane < 4)
    __hip_atomic_store(gow + lane * 32, v, __ATOMIC_RELAXED,
                       __HIP_MEMORY_SCOPE_AGENT);
}

__device__ __forceinline__ void mfma3(float4_ (&acc)[4][2],
                                      const short8& hi, const short8& lo,
                                      const short8 (&wp)[2][2][4],
                                      const int m, const int kb) {
  #pragma unroll
  for (int nt = 0; nt < 2; ++nt) {
    acc[m][nt] = __builtin_amdgcn_mfma_f32_16x16x32_bf16(hi, wp[0][nt][kb], acc[m][nt], 0, 0, 0);
    acc[m][nt] = __builtin_amdgcn_mfma_f32_16x16x32_bf16(lo, wp[0][nt][kb], acc[m][nt], 0, 0, 0);
    acc[m][nt] = __builtin_amdgcn_mfma_f32_16x16x32_bf16(hi, wp[1][nt][kb], acc[m][nt], 0, 0, 0);
  }
}

// packed-ring half-GEMM: plain cached loads (addresses are write-once ->
// cold L1/L2 miss -> coherence-point-fresh fill; NO fences needed)
__device__ __forceinline__ void accum_h(float4_ (&acc)[4][2],
                                        const unsigned* src,
                                        const short8 (&wp)[2][2][4],
                                        const int nn, const int quad,
                                        const int wave) {
  #pragma unroll
  for (int kb = 0; kb < 4; ++kb) {
    const int k0 = wave * 128 + kb * 32 + quad * 8;
    #pragma unroll
    for (int m = 0; m < 4; ++m) {
      const uint8_ u = *(const uint8_*)(src + (size_t)(m * 16 + nn) * H_SZ + k0);
      uint4_ h4, l4;
      #pragma unroll
      for (int r = 0; r < 4; ++r) {
        h4[r] = __builtin_amdgcn_perm(u[2 * r + 1], u[2 * r], 0x05040100u);
        l4[r] = __builtin_amdgcn_perm(u[2 * r + 1], u[2 * r], 0x07060302u);
      }
      const short8 hi = __builtin_bit_cast(short8, h4);
      const short8 lo = __builtin_bit_cast(short8, l4);
      mfma3(acc, hi, lo, wp, m, kb);
    }
  }
}

// fp32-x half-GEMM: on-the-fly split (runs in shadow phase, off critical path)
__device__ __forceinline__ void accum_x(float4_ (&acc)[4][2],
                                        const float* src,
                                        const short8 (&wp)[2][2][4],
                                        const int nn, const int quad,
                                        const int wave) {
  #pragma unroll
  for (int kb = 0; kb < 4; ++kb) {
    const int k0 = wave * 128 + kb * 32 + quad * 8;
    #pragma unroll
    for (int m = 0; m < 4; ++m) {
      const float* p = src + (size_t)(m * 16 + nn) * H_SZ + k0;
      short8 hi, lo;
      #pragma unroll
      for (int j = 0; j < 8; ++j) {
        const float v = p[j];
        const unsigned short h = bf16_rne(v);
        hi[j] = (short)h;
        lo[j] = (short)bf16_rne(v - bf16_to_f32(h));
      }
      mfma3(acc, hi, lo, wp, m, kb);
    }
  }
}

// ---------- persistent LSTM: fence-free, write-once h-ring ----------
// Layer l runs its own t=0..255 among its 128 WGs (RMW-free slot stores +
// leader WG cb==0 publishing go). h(t) lives at ring slot t — every address
// written once, read via plain cached loads at never-touched addresses ->
// always fresh, NO acquire fences, NO L2 invalidation storms.
// Cross-layer gate: layer1 prologue/shadow (reads h0(t)) : go0 >= t+1 / t+2.
// Layer 0 free-runs (no reuse gate — ring has no reuse).
__global__ __launch_bounds__(512, 1)
void lstm_persist(const float* __restrict__ x_in,     // fp32 x [T][B][H]
                  const float* __restrict__ c0_in,
                  const float* __restrict__ Wih,      // fp32 [L][4H][H]
                  const float* __restrict__ Whh,
                  const float* __restrict__ bih,
                  const float* __restrict__ bhh,
                  unsigned* __restrict__ ringp,       // [L][257][B][H] packed
                  float* __restrict__ out,
                  unsigned* __restrict__ bar)
{
  const int wg   = blockIdx.x;
  const int tid  = threadIdx.x;
  const int lane = tid & 63;
  const int wave = tid >> 6;

  const int layer = wg >> 7;
  const int cb    = wg & 127;
  const int nn    = lane & 15;
  const int quad  = lane >> 4;

  __shared__ float lds[8][64][36];

  int growA[2];
  #pragma unroll
  for (int nt = 0; nt < 2; ++nt) {
    const int q = nt * 2 + (nn >> 3);
    growA[nt] = q * H_SZ + cb * 8 + (nn & 7);
  }

  // ---- one-time: fp32 weights -> split-bf16 register fragments
  short8 wreg[2][2][2][4];  // [mat(ih,hh)][plane(hi,lo)][ntile][kb]
  #pragma unroll
  for (int mat = 0; mat < 2; ++mat) {
    const float* wsrc = mat ? Whh : Wih;
    #pragma unroll
    for (int nt = 0; nt < 2; ++nt)
      #pragma unroll
      for (int kb = 0; kb < 4; ++kb) {
        const float* p = wsrc + ((size_t)layer * G4H + growA[nt]) * H_SZ +
                         wave * 128 + kb * 32 + quad * 8;
        short8 hi, lo;
        #pragma unroll
        for (int j = 0; j < 8; ++j) {
          const float v = p[j];
          const unsigned short h = bf16_rne(v);
          hi[j] = (short)h;
          lo[j] = (short)bf16_rne(v - bf16_to_f32(h));
        }
        wreg[mat][0][nt][kb] = hi;
        wreg[mat][1][nt][kb] = lo;
      }
  }

  // ---- reduce-phase mapping + bias preload
  const int rb    = tid >> 3;
  const int rhc   = tid & 7;
  const int rhcol = cb * 8 + rhc;
  float4_ bias4;
  #pragma unroll
  for (int q = 0; q < 4; ++q)
    bias4[q] = bih[layer * G4H + q * H_SZ + rhcol] +
               bhh[layer * G4H + q * H_SZ + rhcol];

  unsigned*       slotp     = bar + layer * 128 + cb;
  const unsigned* slots_own = bar + layer * 128;
  unsigned*       go_own_w  = bar + 256 + layer * 128;
  const unsigned* go_own    = bar + 256 + layer * 128 + ((cb >> 5) & 3) * 32;
  const unsigned* go_oth    = bar + 256 + (1 - layer) * 128 + ((cb >> 5) & 3) * 32;

  const unsigned* ring_own = ringp + (size_t)layer * RING_SLOTS * HB;
  const unsigned* ring_l0  = ringp;

  float creg = 0.f;
  float4_ acc[4][2];
  #pragma unroll
  for (int m = 0; m < 4; ++m)
    #pragma unroll
    for (int nt = 0; nt < 2; ++nt)
      acc[m][nt] = float4_{0.f, 0.f, 0.f, 0.f};

  // ---- prologue: x-side for t=0
  if (layer == 0) {
    accum_x(acc, x_in, wreg[0], nn, quad, wave);
  } else {
    if (tid == 0) poll_ge(go_oth, 1u);                 // h0(0) published
    __syncthreads();
    accum_h(acc, ring_l0 /*slot 0*/, wreg[0], nn, quad, wave);
  }

  #pragma unroll 1
  for (int t = 0; t < T_LEN; ++t) {
    // ---- wait: own-layer h(t-1) complete across the 128 own-layer WGs
    if (t > 0) {
      if (cb == 0) {
        if (wave == 0)
          leader_wait_publish(slots_own, go_own_w, (unsigned)t, lane);
      } else if (tid == 0) {
        poll_ge(go_own, (unsigned)t);
      }
      __syncthreads();
    }

    // ---- recurrent half: h_own(t-1) at slot t-1 (t=0: slot T_LEN = h(-1))
    accum_h(acc, ring_own + (size_t)(t ? t - 1 : T_LEN) * HB,
            wreg[1], nn, quad, wave);

    // ---- partials -> LDS, gate-permuted col = hcol*4 + gate
    #pragma unroll
    for (int m = 0; m < 4; ++m)
      #pragma unroll
      for (int nt = 0; nt < 2; ++nt)
        #pragma unroll
        for (int r = 0; r < 4; ++r)
          lds[wave][m * 16 + quad * 4 + r]
             [((nn & 7) << 2) + nt * 2 + (nn >> 3)] = acc[m][nt][r];
    __syncthreads();

    // ---- reduce over 8 K-waves + fused elementwise
    float4_ g4 = bias4;
    #pragma unroll
    for (int w = 0; w < 8; ++w)
      g4 += *(const float4_*)&lds[w][rb][rhc << 2];
    const float cprev = (t == 0)
        ? c0_in[(size_t)layer * HB + (size_t)rb * H_SZ + rhcol]
        : creg;
    const float ig = 1.f / (1.f + __expf(-g4[0]));
    const float fg = 1.f / (1.f + __expf(-g4[1]));
    const float gg = tanhf(g4[2]);
    const float og = 1.f / (1.f + __expf(-g4[3]));
    const float cn = fg * cprev + ig * gg;
    const float hn = og * tanhf(cn);
    creg = cn;
    const size_t ridx = ((size_t)layer * RING_SLOTS + t) * HB +
                        (size_t)rb * H_SZ + rhcol;
    const unsigned hh = bf16_rne(hn);
    const unsigned ll = bf16_rne(hn - bf16_to_f32((unsigned short)hh));
    __hip_atomic_store(&ringp[ridx], hh | (ll << 16),
                       __ATOMIC_RELAXED, __HIP_MEMORY_SCOPE_AGENT);
    if (layer == 1 && t == T_LEN - 1)
      out[(size_t)rb * H_SZ + rhcol] = hn;

    // ---- arrive: drain ring stores (coherence point), then slot store
    __syncthreads();
    if (tid == 0) {
      __builtin_amdgcn_s_waitcnt(0);
      __hip_atomic_store(slotp, (unsigned)(t + 1),
                         __ATOMIC_RELAXED, __HIP_MEMORY_SCOPE_AGENT);
    }

    // ---- shadow: x-side for t+1 (overlaps own-barrier propagation)
    if (t < T_LEN - 1) {
      if (layer == 1) {
        if (tid == 0) poll_ge(go_oth, (unsigned)(t + 2));  // h0(t+1) ready
        __syncthreads();
      }
      #pragma unroll
      for (int m = 0; m < 4; ++m)
        #pragma unroll
        for (int nt = 0; nt < 2; ++nt)
          acc[m][nt] = float4_{0.f, 0.f, 0.f, 0.f};
      if (layer == 0)
        accum_x(acc, x_in + (size_t)(t + 1) * HB, wreg[0], nn, quad, wave);
      else
        accum_h(acc, ring_l0 + (size_t)(t + 1) * HB,
                wreg[0], nn, quad, wave);
    }
  }

  // ---- epilogue: layer-0 leader publishes go0=256 (layer1's last shadow gate)
  if (layer == 0 && cb == 0 && wave == 0)
    leader_wait_publish(slots_own, go_own_w, (unsigned)T_LEN, lane);
}

extern "C" void kernel_launch(void* const* d_in, const int* in_sizes, int n_in,
                              void* d_out, int out_size, void* d_ws, size_t ws_size,
                              hipStream_t stream) {
  (void)in_sizes; (void)n_in; (void)out_size; (void)ws_size;
  const float* x   = (const float*)d_in[0];
  const float* h0  = (const float*)d_in[1];
  const float* c0  = (const float*)d_in[2];
  const float* Wih = (const float*)d_in[3];
  const float* Whh = (const float*)d_in[4];
  const float* bih = (const float*)d_in[5];
  const float* bhh = (const float*)d_in[6];
  float* out = (float*)d_out;

  // workspace (~128.5 MB): write-once h-ring [L][257][B][H] | bar 4 KB
  char* w = (char*)d_ws;
  unsigned* ringp = (unsigned*)w;
  unsigned* bar   = (unsigned*)(w + (size_t)2 * RING_SLOTS * HB * 4);

  init_h<<<2 * HB / 4 / 256, 256, 0, stream>>>(h0, ringp, bar);
  lstm_persist<<<NBLK, 512, 0, stream>>>(x, c0, Wih, Whh, bih, bhh,
                                         ringp, out, bar);
}

// Round 6
// 4818.005 us; speedup vs baseline: 1.6012x; 1.0302x over previous
//
#include <hip/hip_runtime.h>

#define T_LEN 256
#define B_SZ  64
#define H_SZ  1024
#define G4H   4096
#define HB    (B_SZ * H_SZ)              // 65536
#define NBLK  256                        // compute WGs ONLY
#define RING_SLOTS (T_LEN + 1)           // slot t = h(t); slot T_LEN = h(-1)

typedef __attribute__((ext_vector_type(8))) short short8;
typedef __attribute__((ext_vector_type(4))) float float4_;
typedef __attribute__((ext_vector_type(4))) unsigned int uint4_;
typedef __attribute__((ext_vector_type(8))) unsigned int uint8_;

__device__ __forceinline__ unsigned short bf16_rne(float x) {
  unsigned u = __builtin_bit_cast(unsigned, x);
  unsigned r = u + 0x7FFFu + ((u >> 16) & 1u);
  return (unsigned short)(r >> 16);
}
__device__ __forceinline__ float bf16_to_f32(unsigned short s) {
  unsigned u = ((unsigned)s) << 16;
  return __builtin_bit_cast(float, u);
}

// ---------- prep: h0 -> ring slot T_LEN (t = -1) + zero sync state ----------
__global__ __launch_bounds__(256)
void init_h(const float* __restrict__ h0, unsigned* __restrict__ ringp,
            unsigned* __restrict__ bar) {
  if (blockIdx.x == 0) {
    #pragma unroll
    for (int j = 0; j < 4; ++j) bar[threadIdx.x * 4 + j] = 0u;
  }
  const int e0 = (blockIdx.x * 256 + threadIdx.x) * 4;
  #pragma unroll
  for (int j = 0; j < 4; ++j) {
    const int e = e0 + j;                 // [2][B][H] = 131072 elems
    const int l = e >> 16;
    const int rem = e & (HB - 1);
    const float v = h0[e];
    const unsigned hh = bf16_rne(v);
    const unsigned ll = bf16_rne(v - bf16_to_f32((unsigned short)hh));
    ringp[((size_t)l * RING_SLOTS + T_LEN) * HB + rem] = hh | (ll << 16);
  }
}

// per-wave chunk wait: lanes 0..15 poll the 16 producer slots of this wave's
// K-chunk (one 64 B line); other lanes pass vacuously. Single hop: producer
// slot store -> this poll. No leader, no go-line.
__device__ __forceinline__ void wave_poll_chunk(const unsigned* slots16,
                                               unsigned v, int lane) {
  for (;;) {
    unsigned s = 0xFFFFFFFFu;
    if (lane < 16)
      s = __hip_atomic_load(slots16 + lane, __ATOMIC_RELAXED,
                            __HIP_MEMORY_SCOPE_AGENT);
    if (__all((int)(s >= v))) return;
    __builtin_amdgcn_s_sleep(1);
  }
}

__device__ __forceinline__ void mfma3(float4_ (&acc)[4][2],
                                      const short8& hi, const short8& lo,
                                      const short8 (&wp)[2][2][4],
                                      const int m, const int kb) {
  #pragma unroll
  for (int nt = 0; nt < 2; ++nt) {
    acc[m][nt] = __builtin_amdgcn_mfma_f32_16x16x32_bf16(hi, wp[0][nt][kb], acc[m][nt], 0, 0, 0);
    acc[m][nt] = __builtin_amdgcn_mfma_f32_16x16x32_bf16(lo, wp[0][nt][kb], acc[m][nt], 0, 0, 0);
    acc[m][nt] = __builtin_amdgcn_mfma_f32_16x16x32_bf16(hi, wp[1][nt][kb], acc[m][nt], 0, 0, 0);
  }
}

__device__ __forceinline__ void unpack_mfma(float4_ (&acc)[4][2],
                                            const uint8_& u,
                                            const short8 (&wp)[2][2][4],
                                            const int m, const int kb) {
  uint4_ h4, l4;
  #pragma unroll
  for (int r = 0; r < 4; ++r) {
    h4[r] = __builtin_amdgcn_perm(u[2 * r + 1], u[2 * r], 0x05040100u);
    l4[r] = __builtin_amdgcn_perm(u[2 * r + 1], u[2 * r], 0x07060302u);
  }
  const short8 hi = __builtin_bit_cast(short8, h4);
  const short8 lo = __builtin_bit_cast(short8, l4);
  mfma3(acc, hi, lo, wp, m, kb);
}

// packed-ring half-GEMM: plain cached loads (write-once addresses -> cold
// miss -> coherence-point-fresh; no fences), 4-row register double buffer.
__device__ __forceinline__ void accum_h(float4_ (&acc)[4][2],
                                        const unsigned* src,
                                        const short8 (&wp)[2][2][4],
                                        const int nn, const int quad,
                                        const int wave) {
  uint8_ ua[4], ub[4];
  const int kbase = wave * 128 + quad * 8;
  #pragma unroll
  for (int m = 0; m < 4; ++m)
    ua[m] = *(const uint8_*)(src + (size_t)(m * 16 + nn) * H_SZ + kbase);
  #pragma unroll
  for (int kb = 0; kb < 4; ++kb) {
    uint8_* cur = (kb & 1) ? ub : ua;
    uint8_* nxt = (kb & 1) ? ua : ub;
    if (kb < 3) {
      #pragma unroll
      for (int m = 0; m < 4; ++m)
        nxt[m] = *(const uint8_*)(src + (size_t)(m * 16 + nn) * H_SZ +
                                  kbase + (kb + 1) * 32);
    }
    #pragma unroll
    for (int m = 0; m < 4; ++m)
      unpack_mfma(acc, cur[m], wp, m, kb);
  }
}

// fp32-x half-GEMM: on-the-fly split (runs in shadow phase, off critical path)
__device__ __forceinline__ void accum_x(float4_ (&acc)[4][2],
                                        const float* src,
                                        const short8 (&wp)[2][2][4],
                                        const int nn, const int quad,
                                        const int wave) {
  #pragma unroll
  for (int kb = 0; kb < 4; ++kb) {
    const int k0 = wave * 128 + kb * 32 + quad * 8;
    #pragma unroll
    for (int m = 0; m < 4; ++m) {
      const float* p = src + (size_t)(m * 16 + nn) * H_SZ + k0;
      short8 hi, lo;
      #pragma unroll
      for (int j = 0; j < 8; ++j) {
        const float v = p[j];
        const unsigned short h = bf16_rne(v);
        hi[j] = (short)h;
        lo[j] = (short)bf16_rne(v - bf16_to_f32(h));
      }
      mfma3(acc, hi, lo, wp, m, kb);
    }
  }
}

// ---------- persistent LSTM: single-hop per-wave chunk sync ----------
// h(t) at ring slot t (write-once). Producer WG (l,cb) owns hcols
// [8cb,8cb+8); after step t it stores slot[l*128+cb]=t+1. Consumer wave v
// needs only h-cols [128v,128v+128) = producers cb in [16v,16v+16): it polls
// that 64 B slot line DIRECTLY and proceeds alone — one flag hop, join over
// 16 producers (not 128), waves self-destagger. No leader, no go, no fences.
// Cross-layer: layer-1 x-side reads h0(t+1) gated the same way (>= t+2).
__global__ __launch_bounds__(512, 1)
void lstm_persist(const float* __restrict__ x_in,     // fp32 x [T][B][H]
                  const float* __restrict__ c0_in,
                  const float* __restrict__ Wih,      // fp32 [L][4H][H]
                  const float* __restrict__ Whh,
                  const float* __restrict__ bih,
                  const float* __restrict__ bhh,
                  unsigned* __restrict__ ringp,       // [L][257][B][H] packed
                  float* __restrict__ out,
                  unsigned* __restrict__ bar)
{
  const int wg   = blockIdx.x;
  const int tid  = threadIdx.x;
  const int lane = tid & 63;
  const int wave = tid >> 6;

  const int layer = wg >> 7;
  const int cb    = wg & 127;
  const int nn    = lane & 15;
  const int quad  = lane >> 4;

  __shared__ float lds[8][64][36];

  int growA[2];
  #pragma unroll
  for (int nt = 0; nt < 2; ++nt) {
    const int q = nt * 2 + (nn >> 3);
    growA[nt] = q * H_SZ + cb * 8 + (nn & 7);
  }

  // ---- one-time: fp32 weights -> split-bf16 register fragments
  short8 wreg[2][2][2][4];  // [mat(ih,hh)][plane(hi,lo)][ntile][kb]
  #pragma unroll
  for (int mat = 0; mat < 2; ++mat) {
    const float* wsrc = mat ? Whh : Wih;
    #pragma unroll
    for (int nt = 0; nt < 2; ++nt)
      #pragma unroll
      for (int kb = 0; kb < 4; ++kb) {
        const float* p = wsrc + ((size_t)layer * G4H + growA[nt]) * H_SZ +
                         wave * 128 + kb * 32 + quad * 8;
        short8 hi, lo;
        #pragma unroll
        for (int j = 0; j < 8; ++j) {
          const float v = p[j];
          const unsigned short h = bf16_rne(v);
          hi[j] = (short)h;
          lo[j] = (short)bf16_rne(v - bf16_to_f32(h));
        }
        wreg[mat][0][nt][kb] = hi;
        wreg[mat][1][nt][kb] = lo;
      }
  }

  // ---- reduce-phase mapping + bias preload
  const int rb    = tid >> 3;
  const int rhc   = tid & 7;
  const int rhcol = cb * 8 + rhc;
  float4_ bias4;
  #pragma unroll
  for (int q = 0; q < 4; ++q)
    bias4[q] = bih[layer * G4H + q * H_SZ + rhcol] +
               bhh[layer * G4H + q * H_SZ + rhcol];

  unsigned*       slotp      = bar + layer * 128 + cb;       // my producer slot
  const unsigned* chunk_own  = bar + layer * 128 + wave * 16; // my K-chunk's producers
  const unsigned* chunk_l0   = bar + wave * 16;               // layer-0 chunk (for L1)

  const unsigned* ring_own = ringp + (size_t)layer * RING_SLOTS * HB;
  const unsigned* ring_l0  = ringp;

  float creg = 0.f;
  float4_ acc[4][2];
  #pragma unroll
  for (int m = 0; m < 4; ++m)
    #pragma unroll
    for (int nt = 0; nt < 2; ++nt)
      acc[m][nt] = float4_{0.f, 0.f, 0.f, 0.f};

  // ---- prologue: x-side for t=0 (per-wave gate for layer 1)
  if (layer == 0) {
    accum_x(acc, x_in, wreg[0], nn, quad, wave);
  } else {
    wave_poll_chunk(chunk_l0, 1u, lane);               // h0(0) chunk ready
    accum_h(acc, ring_l0 /*slot 0*/, wreg[0], nn, quad, wave);
  }

  #pragma unroll 1
  for (int t = 0; t < T_LEN; ++t) {
    // ---- per-wave wait: my chunk of h_own(t-1) ready; then go alone
    if (t > 0)
      wave_poll_chunk(chunk_own, (unsigned)t, lane);

    // ---- recurrent half: h_own(t-1) at slot t-1 (t=0: slot T_LEN = h(-1))
    accum_h(acc, ring_own + (size_t)(t ? t - 1 : T_LEN) * HB,
            wreg[1], nn, quad, wave);

    // ---- partials -> LDS, gate-permuted col = hcol*4 + gate
    #pragma unroll
    for (int m = 0; m < 4; ++m)
      #pragma unroll
      for (int nt = 0; nt < 2; ++nt)
        #pragma unroll
        for (int r = 0; r < 4; ++r)
          lds[wave][m * 16 + quad * 4 + r]
             [((nn & 7) << 2) + nt * 2 + (nn >> 3)] = acc[m][nt][r];
    __syncthreads();

    // ---- reduce over 8 K-waves + fused elementwise
    float4_ g4 = bias4;
    #pragma unroll
    for (int w = 0; w < 8; ++w)
      g4 += *(const float4_*)&lds[w][rb][rhc << 2];
    const float cprev = (t == 0)
        ? c0_in[(size_t)layer * HB + (size_t)rb * H_SZ + rhcol]
        : creg;
    const float ig = 1.f / (1.f + __expf(-g4[0]));
    const float fg = 1.f / (1.f + __expf(-g4[1]));
    const float gg = tanhf(g4[2]);
    const float og = 1.f / (1.f + __expf(-g4[3]));
    const float cn = fg * cprev + ig * gg;
    const float hn = og * tanhf(cn);
    creg = cn;
    const size_t ridx = ((size_t)layer * RING_SLOTS + t) * HB +
                        (size_t)rb * H_SZ + rhcol;
    const unsigned hh = bf16_rne(hn);
    const unsigned ll = bf16_rne(hn - bf16_to_f32((unsigned short)hh));
    __hip_atomic_store(&ringp[ridx], hh | (ll << 16),
                       __ATOMIC_RELAXED, __HIP_MEMORY_SCOPE_AGENT);
    if (layer == 1 && t == T_LEN - 1)
      out[(size_t)rb * H_SZ + rhcol] = hn;

    // ---- arrive: barrier drains every wave's ring stores, then flag store
    __syncthreads();
    if (tid == 0) {
      __builtin_amdgcn_s_waitcnt(0);
      __hip_atomic_store(slotp, (unsigned)(t + 1),
                         __ATOMIC_RELAXED, __HIP_MEMORY_SCOPE_AGENT);
    }

    // ---- shadow: x-side for t+1 (overlaps flag propagation; per-wave gate)
    if (t < T_LEN - 1) {
      #pragma unroll
      for (int m = 0; m < 4; ++m)
        #pragma unroll
        for (int nt = 0; nt < 2; ++nt)
          acc[m][nt] = float4_{0.f, 0.f, 0.f, 0.f};
      if (layer == 0) {
        accum_x(acc, x_in + (size_t)(t + 1) * HB, wreg[0], nn, quad, wave);
      } else {
        wave_poll_chunk(chunk_l0, (unsigned)(t + 2), lane); // h0(t+1) chunk
        accum_h(acc, ring_l0 + (size_t)(t + 1) * HB,
                wreg[0], nn, quad, wave);
      }
    }
  }
}

extern "C" void kernel_launch(void* const* d_in, const int* in_sizes, int n_in,
                              void* d_out, int out_size, void* d_ws, size_t ws_size,
                              hipStream_t stream) {
  (void)in_sizes; (void)n_in; (void)out_size; (void)ws_size;
  const float* x   = (const float*)d_in[0];
  const float* h0  = (const float*)d_in[1];
  const float* c0  = (const float*)d_in[2];
  const float* Wih = (const float*)d_in[3];
  const float* Whh = (const float*)d_in[4];
  const float* bih = (const float*)d_in[5];
  const float* bhh = (const float*)d_in[6];
  float* out = (float*)d_out;

  // workspace (~134.5 MB): write-once h-ring [L][257][B][H] | bar 4 KB
  char* w = (char*)d_ws;
  unsigned* ringp = (unsigned*)w;
  unsigned* bar   = (unsigned*)(w + (size_t)2 * RING_SLOTS * HB * 4);

  init_h<<<2 * HB / 4 / 256, 256, 0, stream>>>(h0, ringp, bar);
  lstm_persist<<<NBLK, 512, 0, stream>>>(x, c0, Wih, Whh, bih, bhh,
                                         ringp, out, bar);
}

// Round 7
// 4284.082 us; speedup vs baseline: 1.8007x; 1.1246x over previous
//
#include <hip/hip_runtime.h>

#define T_LEN 256
#define B_SZ  64
#define H_SZ  1024
#define G4H   4096
#define HB    (B_SZ * H_SZ)              // 65536
#define NBLK  256                        // compute WGs ONLY
#define RING_SLOTS (T_LEN + 1)           // slot t = h(t); slot T_LEN = h(-1)

typedef __attribute__((ext_vector_type(8))) short short8;
typedef __attribute__((ext_vector_type(4))) float float4_;
typedef __attribute__((ext_vector_type(4))) unsigned int uint4_;

__device__ __forceinline__ unsigned short bf16_rne(float x) {
  unsigned u = __builtin_bit_cast(unsigned, x);
  unsigned r = u + 0x7FFFu + ((u >> 16) & 1u);
  return (unsigned short)(r >> 16);
}
__device__ __forceinline__ float bf16_to_f32(unsigned short s) {
  unsigned u = ((unsigned)s) << 16;
  return __builtin_bit_cast(float, u);
}

// ---------- prep: h0 -> bf16 ring slot T_LEN (t = -1) + zero sync state -----
__global__ __launch_bounds__(256)
void init_h(const float* __restrict__ h0, unsigned short* __restrict__ ringb,
            unsigned* __restrict__ bar) {
  if (blockIdx.x == 0) {
    #pragma unroll
    for (int j = 0; j < 4; ++j) bar[threadIdx.x * 4 + j] = 0u;
  }
  const int e0 = (blockIdx.x * 256 + threadIdx.x) * 4;
  #pragma unroll
  for (int j = 0; j < 4; ++j) {
    const int e = e0 + j;                 // [2][B][H] = 131072 elems
    const int l = e >> 16;
    const int rem = e & (HB - 1);
    ringb[((size_t)l * RING_SLOTS + T_LEN) * HB + rem] = bf16_rne(h0[e]);
  }
}

// per-wave chunk wait: lanes 0..15 poll the 16 producer slots of this wave's
// K-chunk (one 64 B line); single hop producer-store -> this poll.
__device__ __forceinline__ void wave_poll_chunk(const unsigned* slots16,
                                               unsigned v, int lane) {
  for (;;) {
    unsigned s = 0xFFFFFFFFu;
    if (lane < 16)
      s = __hip_atomic_load(slots16 + lane, __ATOMIC_RELAXED,
                            __HIP_MEMORY_SCOPE_AGENT);
    if (__all((int)(s >= v))) return;
    __builtin_amdgcn_s_sleep(1);
  }
}

__device__ __forceinline__ void mfma3(float4_ (&acc)[4][2],
                                      const short8& hi, const short8& lo,
                                      const short8 (&wp)[2][2][4],
                                      const int m, const int kb) {
  #pragma unroll
  for (int nt = 0; nt < 2; ++nt) {
    acc[m][nt] = __builtin_amdgcn_mfma_f32_16x16x32_bf16(hi, wp[0][nt][kb], acc[m][nt], 0, 0, 0);
    acc[m][nt] = __builtin_amdgcn_mfma_f32_16x16x32_bf16(lo, wp[0][nt][kb], acc[m][nt], 0, 0, 0);
    acc[m][nt] = __builtin_amdgcn_mfma_f32_16x16x32_bf16(hi, wp[1][nt][kb], acc[m][nt], 0, 0, 0);
  }
}

// bf16-ring half-GEMM: a short8 load IS the A-fragment (no unpack), 2 MFMAs
// per fragment (a*W_hi + a*W_lo). 16 loads issued before first MFMA -> MLP.
__device__ __forceinline__ void accum_hb(float4_ (&acc)[4][2],
                                         const unsigned short* src,
                                         const short8 (&wp)[2][2][4],
                                         const int nn, const int quad,
                                         const int wave) {
  const int kbase = wave * 128 + quad * 8;
  short8 va[8], vb[8];
  #pragma unroll
  for (int kb = 0; kb < 2; ++kb)
    #pragma unroll
    for (int m = 0; m < 4; ++m)
      va[kb * 4 + m] = *(const short8*)(src + (size_t)(m * 16 + nn) * H_SZ +
                                        kbase + kb * 32);
  #pragma unroll
  for (int kb = 0; kb < 2; ++kb)
    #pragma unroll
    for (int m = 0; m < 4; ++m)
      vb[kb * 4 + m] = *(const short8*)(src + (size_t)(m * 16 + nn) * H_SZ +
                                        kbase + (kb + 2) * 32);
  #pragma unroll
  for (int kb = 0; kb < 2; ++kb)
    #pragma unroll
    for (int m = 0; m < 4; ++m)
      #pragma unroll
      for (int nt = 0; nt < 2; ++nt) {
        acc[m][nt] = __builtin_amdgcn_mfma_f32_16x16x32_bf16(va[kb * 4 + m], wp[0][nt][kb], acc[m][nt], 0, 0, 0);
        acc[m][nt] = __builtin_amdgcn_mfma_f32_16x16x32_bf16(va[kb * 4 + m], wp[1][nt][kb], acc[m][nt], 0, 0, 0);
      }
  #pragma unroll
  for (int kb = 0; kb < 2; ++kb)
    #pragma unroll
    for (int m = 0; m < 4; ++m)
      #pragma unroll
      for (int nt = 0; nt < 2; ++nt) {
        acc[m][nt] = __builtin_amdgcn_mfma_f32_16x16x32_bf16(vb[kb * 4 + m], wp[0][nt][kb + 2], acc[m][nt], 0, 0, 0);
        acc[m][nt] = __builtin_amdgcn_mfma_f32_16x16x32_bf16(vb[kb * 4 + m], wp[1][nt][kb + 2], acc[m][nt], 0, 0, 0);
      }
}

// fp32-x half-GEMM: on-the-fly split (runs in shadow phase, off critical path)
__device__ __forceinline__ void accum_x(float4_ (&acc)[4][2],
                                        const float* src,
                                        const short8 (&wp)[2][2][4],
                                        const int nn, const int quad,
                                        const int wave) {
  #pragma unroll
  for (int kb = 0; kb < 4; ++kb) {
    const int k0 = wave * 128 + kb * 32 + quad * 8;
    #pragma unroll
    for (int m = 0; m < 4; ++m) {
      const float* p = src + (size_t)(m * 16 + nn) * H_SZ + k0;
      short8 hi, lo;
      #pragma unroll
      for (int j = 0; j < 8; ++j) {
        const float v = p[j];
        const unsigned short h = bf16_rne(v);
        hi[j] = (short)h;
        lo[j] = (short)bf16_rne(v - bf16_to_f32(h));
      }
      mfma3(acc, hi, lo, wp, m, kb);
    }
  }
}

// ---------- persistent LSTM: bf16 write-once ring, per-wave chunk sync ------
// h(t) at bf16 ring slot t (write-once, fence-free: cold-miss reads are
// coherence-fresh). Producer WG (l,cb) owns hcols [8cb,8cb+8); flags
// slot[l*128+cb]=t+1 after drain. Consumer wave v polls its 16 producers.
// Critical path per step: poll -> 16x16B loads -> 64 MFMA -> reduce -> store.
__global__ __launch_bounds__(512, 1)
void lstm_persist(const float* __restrict__ x_in,     // fp32 x [T][B][H]
                  const float* __restrict__ c0_in,
                  const float* __restrict__ Wih,      // fp32 [L][4H][H]
                  const float* __restrict__ Whh,
                  const float* __restrict__ bih,
                  const float* __restrict__ bhh,
                  unsigned short* __restrict__ ringb, // [L][257][B][H] bf16
                  float* __restrict__ out,
                  unsigned* __restrict__ bar)
{
  const int wg   = blockIdx.x;
  const int tid  = threadIdx.x;
  const int lane = tid & 63;
  const int wave = tid >> 6;

  const int layer = wg >> 7;
  const int cb    = wg & 127;
  const int nn    = lane & 15;
  const int quad  = lane >> 4;

  __shared__ float lds[8][64][36];

  int growA[2];
  #pragma unroll
  for (int nt = 0; nt < 2; ++nt) {
    const int q = nt * 2 + (nn >> 3);
    growA[nt] = q * H_SZ + cb * 8 + (nn & 7);
  }

  // ---- one-time: fp32 weights -> split-bf16 register fragments
  short8 wreg[2][2][2][4];  // [mat(ih,hh)][plane(hi,lo)][ntile][kb]
  #pragma unroll
  for (int mat = 0; mat < 2; ++mat) {
    const float* wsrc = mat ? Whh : Wih;
    #pragma unroll
    for (int nt = 0; nt < 2; ++nt)
      #pragma unroll
      for (int kb = 0; kb < 4; ++kb) {
        const float* p = wsrc + ((size_t)layer * G4H + growA[nt]) * H_SZ +
                         wave * 128 + kb * 32 + quad * 8;
        short8 hi, lo;
        #pragma unroll
        for (int j = 0; j < 8; ++j) {
          const float v = p[j];
          const unsigned short h = bf16_rne(v);
          hi[j] = (short)h;
          lo[j] = (short)bf16_rne(v - bf16_to_f32(h));
        }
        wreg[mat][0][nt][kb] = hi;
        wreg[mat][1][nt][kb] = lo;
      }
  }

  // ---- elementwise mapping: threads 0..255, each owns (batch, 2 hcols)
  const int eb   = tid >> 2;          // 0..127 (valid < 64 when tid < 256)
  const int ec   = (tid & 3) * 2;     // local col pair base: 0,2,4,6
  const int ecol = cb * 8 + ec;
  float4_ biasA, biasB;
  #pragma unroll
  for (int q = 0; q < 4; ++q) {
    biasA[q] = bih[layer * G4H + q * H_SZ + ecol] +
               bhh[layer * G4H + q * H_SZ + ecol];
    biasB[q] = bih[layer * G4H + q * H_SZ + ecol + 1] +
               bhh[layer * G4H + q * H_SZ + ecol + 1];
  }

  unsigned*       slotp     = bar + layer * 128 + cb;        // my producer slot
  const unsigned* chunk_own = bar + layer * 128 + wave * 16; // my K-chunk producers
  const unsigned* chunk_l0  = bar + wave * 16;               // layer-0 chunk

  const unsigned short* ring_own = ringb + (size_t)layer * RING_SLOTS * HB;
  const unsigned short* ring_l0  = ringb;

  float cA = 0.f, cB = 0.f;
  float4_ acc[4][2];
  #pragma unroll
  for (int m = 0; m < 4; ++m)
    #pragma unroll
    for (int nt = 0; nt < 2; ++nt)
      acc[m][nt] = float4_{0.f, 0.f, 0.f, 0.f};

  // ---- prologue: x-side for t=0 (per-wave gate for layer 1)
  if (layer == 0) {
    accum_x(acc, x_in, wreg[0], nn, quad, wave);
  } else {
    wave_poll_chunk(chunk_l0, 1u, lane);               // h0(0) chunk ready
    accum_hb(acc, ring_l0 /*slot 0*/, wreg[0], nn, quad, wave);
  }

  #pragma unroll 1
  for (int t = 0; t < T_LEN; ++t) {
    // ---- per-wave wait: my chunk of h_own(t-1) ready; then go alone
    if (t > 0)
      wave_poll_chunk(chunk_own, (unsigned)t, lane);

    // ---- recurrent half: h_own(t-1) at slot t-1 (t=0: slot T_LEN = h(-1))
    accum_hb(acc, ring_own + (size_t)(t ? t - 1 : T_LEN) * HB,
             wreg[1], nn, quad, wave);

    // ---- partials -> LDS, gate-permuted col = hcol*4 + gate
    #pragma unroll
    for (int m = 0; m < 4; ++m)
      #pragma unroll
      for (int nt = 0; nt < 2; ++nt)
        #pragma unroll
        for (int r = 0; r < 4; ++r)
          lds[wave][m * 16 + quad * 4 + r]
             [((nn & 7) << 2) + nt * 2 + (nn >> 3)] = acc[m][nt][r];
    __syncthreads();

    // ---- reduce over 8 K-waves + fused elementwise (2 cols/thread)
    if (tid < 256) {
      float4_ gA = biasA, gB = biasB;
      #pragma unroll
      for (int w = 0; w < 8; ++w) {
        gA += *(const float4_*)&lds[w][eb][ec * 4];
        gB += *(const float4_*)&lds[w][eb][ec * 4 + 4];
      }
      float cpA, cpB;
      if (t == 0) {
        cpA = c0_in[(size_t)layer * HB + (size_t)eb * H_SZ + ecol];
        cpB = c0_in[(size_t)layer * HB + (size_t)eb * H_SZ + ecol + 1];
      } else { cpA = cA; cpB = cB; }
      const float igA = 1.f / (1.f + __expf(-gA[0]));
      const float fgA = 1.f / (1.f + __expf(-gA[1]));
      const float ggA = tanhf(gA[2]);
      const float ogA = 1.f / (1.f + __expf(-gA[3]));
      const float cnA = fgA * cpA + igA * ggA;
      const float hnA = ogA * tanhf(cnA);
      const float igB = 1.f / (1.f + __expf(-gB[0]));
      const float fgB = 1.f / (1.f + __expf(-gB[1]));
      const float ggB = tanhf(gB[2]);
      const float ogB = 1.f / (1.f + __expf(-gB[3]));
      const float cnB = fgB * cpB + igB * ggB;
      const float hnB = ogB * tanhf(cnB);
      cA = cnA; cB = cnB;
      const size_t ridx = ((size_t)layer * RING_SLOTS + t) * HB +
                          (size_t)eb * H_SZ + ecol;     // even -> 4B aligned
      const unsigned pk = (unsigned)bf16_rne(hnA) |
                          ((unsigned)bf16_rne(hnB) << 16);
      __hip_atomic_store((unsigned*)(ringb + ridx), pk,
                         __ATOMIC_RELAXED, __HIP_MEMORY_SCOPE_AGENT);
      if (layer == 1 && t == T_LEN - 1) {
        out[(size_t)eb * H_SZ + ecol]     = hnA;
        out[(size_t)eb * H_SZ + ecol + 1] = hnB;
      }
    }

    // ---- arrive: barrier drains storing waves' ring stores, then flag
    __syncthreads();
    if (tid == 0) {
      __builtin_amdgcn_s_waitcnt(0);
      __hip_atomic_store(slotp, (unsigned)(t + 1),
                         __ATOMIC_RELAXED, __HIP_MEMORY_SCOPE_AGENT);
    }

    // ---- shadow: x-side for t+1 (overlaps flag propagation; per-wave gate)
    if (t < T_LEN - 1) {
      #pragma unroll
      for (int m = 0; m < 4; ++m)
        #pragma unroll
        for (int nt = 0; nt < 2; ++nt)
          acc[m][nt] = float4_{0.f, 0.f, 0.f, 0.f};
      if (layer == 0) {
        accum_x(acc, x_in + (size_t)(t + 1) * HB, wreg[0], nn, quad, wave);
      } else {
        wave_poll_chunk(chunk_l0, (unsigned)(t + 2), lane); // h0(t+1) chunk
        accum_hb(acc, ring_l0 + (size_t)(t + 1) * HB,
                 wreg[0], nn, quad, wave);
      }
    }
  }
}

extern "C" void kernel_launch(void* const* d_in, const int* in_sizes, int n_in,
                              void* d_out, int out_size, void* d_ws, size_t ws_size,
                              hipStream_t stream) {
  (void)in_sizes; (void)n_in; (void)out_size; (void)ws_size;
  const float* x   = (const float*)d_in[0];
  const float* h0  = (const float*)d_in[1];
  const float* c0  = (const float*)d_in[2];
  const float* Wih = (const float*)d_in[3];
  const float* Whh = (const float*)d_in[4];
  const float* bih = (const float*)d_in[5];
  const float* bhh = (const float*)d_in[6];
  float* out = (float*)d_out;

  // workspace (~67.4 MB): bf16 write-once h-ring [L][257][B][H] | bar 4 KB
  char* w = (char*)d_ws;
  unsigned short* ringb = (unsigned short*)w;
  unsigned*       bar   = (unsigned*)(w + (size_t)2 * RING_SLOTS * HB * 2);

  init_h<<<2 * HB / 4 / 256, 256, 0, stream>>>(h0, ringb, bar);
  lstm_persist<<<NBLK, 512, 0, stream>>>(x, c0, Wih, Whh, bih, bhh,
                                         ringb, out, bar);
}

// Round 8
// 3674.501 us; speedup vs baseline: 2.0995x; 1.1659x over previous
//
#include <hip/hip_runtime.h>

#define T_LEN 256
#define B_SZ  64
#define H_SZ  1024
#define G4H   4096
#define HB    (B_SZ * H_SZ)              // 65536
#define NBLK  256                        // compute WGs ONLY
#define RING_SLOTS (T_LEN + 1)           // slot t = h(t); slot T_LEN = h(-1)

typedef __attribute__((ext_vector_type(8))) short short8;
typedef __attribute__((ext_vector_type(4))) float float4_;
typedef __attribute__((ext_vector_type(4))) unsigned int uint4_;
typedef __attribute__((ext_vector_type(8))) unsigned int uint8_;

__device__ __forceinline__ unsigned short bf16_rne(float x) {
  unsigned u = __builtin_bit_cast(unsigned, x);
  unsigned r = u + 0x7FFFu + ((u >> 16) & 1u);
  return (unsigned short)(r >> 16);
}
__device__ __forceinline__ float bf16_to_f32(unsigned short s) {
  unsigned u = ((unsigned)s) << 16;
  return __builtin_bit_cast(float, u);
}

// ---------- prep: x fp32 -> packed split-bf16 (hi | lo<<16) dwords ----------
__global__ __launch_bounds__(256)
void pack_x(const float* __restrict__ src, unsigned* __restrict__ dst) {
  const size_t i = ((size_t)blockIdx.x * 256 + threadIdx.x) * 4;
  float4_ v = *(const float4_*)(src + i);
  uint4_ o;
  #pragma unroll
  for (int j = 0; j < 4; ++j) {
    const unsigned short h = bf16_rne(v[j]);
    const unsigned short l = bf16_rne(v[j] - bf16_to_f32(h));
    o[j] = (unsigned)h | ((unsigned)l << 16);
  }
  *(uint4_*)(dst + i) = o;
}

// ---------- prep: h0 -> bf16 ring slot T_LEN (t = -1) + zero sub-flags ------
__global__ __launch_bounds__(256)
void init_h(const float* __restrict__ h0, unsigned short* __restrict__ ringb,
            unsigned* __restrict__ bar) {
  if (blockIdx.x == 0) {
    #pragma unroll
    for (int j = 0; j < 4; ++j) bar[threadIdx.x * 4 + j] = 0u;  // [2][128][4]
  }
  const int e0 = (blockIdx.x * 256 + threadIdx.x) * 4;
  #pragma unroll
  for (int j = 0; j < 4; ++j) {
    const int e = e0 + j;                 // [2][B][H] = 131072 elems
    const int l = e >> 16;
    const int rem = e & (HB - 1);
    ringb[((size_t)l * RING_SLOTS + T_LEN) * HB + rem] = bf16_rne(h0[e]);
  }
}

// wave polls 64 contiguous sub-flag dwords (16 producer WGs x 4 waves), 1/lane
__device__ __forceinline__ void wave_poll64(const unsigned* s64, unsigned v,
                                            int lane) {
  for (;;) {
    const unsigned s = __hip_atomic_load(s64 + lane, __ATOMIC_RELAXED,
                                         __HIP_MEMORY_SCOPE_AGENT);
    if (__all((int)(s >= v))) return;
    __builtin_amdgcn_s_sleep(1);
  }
}

// bf16-ring half-GEMM: 16 loads issued up-front (deep MLP), then 64 MFMA.
__device__ __forceinline__ void accum_hb(float4_ (&acc)[4][2],
                                         const unsigned short* src,
                                         const short8 (&wp)[2][2][4],
                                         const int nn, const int quad,
                                         const int wave) {
  const int kbase = wave * 128 + quad * 8;
  short8 v[16];
  #pragma unroll
  for (int kb = 0; kb < 4; ++kb)
    #pragma unroll
    for (int m = 0; m < 4; ++m)
      v[kb * 4 + m] = *(const short8*)(src + (size_t)(m * 16 + nn) * H_SZ +
                                       kbase + kb * 32);
  #pragma unroll
  for (int kb = 0; kb < 4; ++kb)
    #pragma unroll
    for (int m = 0; m < 4; ++m)
      #pragma unroll
      for (int nt = 0; nt < 2; ++nt) {
        acc[m][nt] = __builtin_amdgcn_mfma_f32_16x16x32_bf16(v[kb * 4 + m], wp[0][nt][kb], acc[m][nt], 0, 0, 0);
        acc[m][nt] = __builtin_amdgcn_mfma_f32_16x16x32_bf16(v[kb * 4 + m], wp[1][nt][kb], acc[m][nt], 0, 0, 0);
      }
}

// packed split-x half-GEMM: perm unpack (8 inst/fragment), 96 MFMA.
__device__ __forceinline__ void accum_xp(float4_ (&acc)[4][2],
                                         const unsigned* src,
                                         const short8 (&wp)[2][2][4],
                                         const int nn, const int quad,
                                         const int wave) {
  #pragma unroll
  for (int kb = 0; kb < 4; ++kb) {
    const int k0 = wave * 128 + kb * 32 + quad * 8;
    #pragma unroll
    for (int m = 0; m < 4; ++m) {
      const uint8_ u = *(const uint8_*)(src + (size_t)(m * 16 + nn) * H_SZ + k0);
      uint4_ h4, l4;
      #pragma unroll
      for (int r = 0; r < 4; ++r) {
        h4[r] = __builtin_amdgcn_perm(u[2 * r + 1], u[2 * r], 0x05040100u);
        l4[r] = __builtin_amdgcn_perm(u[2 * r + 1], u[2 * r], 0x07060302u);
      }
      const short8 hi = __builtin_bit_cast(short8, h4);
      const short8 lo = __builtin_bit_cast(short8, l4);
      #pragma unroll
      for (int nt = 0; nt < 2; ++nt) {
        acc[m][nt] = __builtin_amdgcn_mfma_f32_16x16x32_bf16(hi, wp[0][nt][kb], acc[m][nt], 0, 0, 0);
        acc[m][nt] = __builtin_amdgcn_mfma_f32_16x16x32_bf16(lo, wp[0][nt][kb], acc[m][nt], 0, 0, 0);
        acc[m][nt] = __builtin_amdgcn_mfma_f32_16x16x32_bf16(hi, wp[1][nt][kb], acc[m][nt], 0, 0, 0);
      }
    }
  }
}

// ---------- persistent LSTM: single-barrier step, per-wave sub-flags --------
// h(t) at bf16 ring slot t (write-once, fence-free). Producer WG (l,cb) owns
// hcols [8cb,8cb+8); its waves 0-3 each own 16 batches of the elementwise and
// raise flag[l][cb][wave]=t+1 after their OWN stores drain (no 2nd barrier,
// no whole-WG convoy). Consumer wave v polls its chunk's 64 sub-flags (1 per
// lane). LDS is double-buffered by t&1 so the barrier-free tail can't race.
__global__ __launch_bounds__(512, 1)
void lstm_persist(const unsigned* __restrict__ xp,     // packed x [T][B][H]
                  const float* __restrict__ c0_in,
                  const float* __restrict__ Wih,       // fp32 [L][4H][H]
                  const float* __restrict__ Whh,
                  const float* __restrict__ bih,
                  const float* __restrict__ bhh,
                  unsigned short* __restrict__ ringb,  // [L][257][B][H] bf16
                  float* __restrict__ out,
                  unsigned* __restrict__ bar)          // [2][128][4] sub-flags
{
  const int wg   = blockIdx.x;
  const int tid  = threadIdx.x;
  const int lane = tid & 63;
  const int wave = tid >> 6;

  const int layer = wg >> 7;
  const int cb    = wg & 127;
  const int nn    = lane & 15;
  const int quad  = lane >> 4;

  __shared__ float lds[2][8][64][36];   // 144 KB (double-buffered by t&1)

  int growA[2];
  #pragma unroll
  for (int nt = 0; nt < 2; ++nt) {
    const int q = nt * 2 + (nn >> 3);
    growA[nt] = q * H_SZ + cb * 8 + (nn & 7);
  }

  // ---- one-time: fp32 weights -> split-bf16 register fragments
  short8 wreg[2][2][2][4];  // [mat(ih,hh)][plane(hi,lo)][ntile][kb]
  #pragma unroll
  for (int mat = 0; mat < 2; ++mat) {
    const float* wsrc = mat ? Whh : Wih;
    #pragma unroll
    for (int nt = 0; nt < 2; ++nt)
      #pragma unroll
      for (int kb = 0; kb < 4; ++kb) {
        const float* p = wsrc + ((size_t)layer * G4H + growA[nt]) * H_SZ +
                         wave * 128 + kb * 32 + quad * 8;
        short8 hi, lo;
        #pragma unroll
        for (int j = 0; j < 8; ++j) {
          const float v = p[j];
          const unsigned short h = bf16_rne(v);
          hi[j] = (short)h;
          lo[j] = (short)bf16_rne(v - bf16_to_f32(h));
        }
        wreg[mat][0][nt][kb] = hi;
        wreg[mat][1][nt][kb] = lo;
      }
  }

  // ---- elementwise mapping (waves 0-3): wave owns batches [16w,16w+16)
  const int eb   = wave * 16 + (lane >> 2);   // batch (valid for wave<4)
  const int ec   = (lane & 3) * 2;            // local col pair
  const int ecol = cb * 8 + ec;
  float4_ biasA, biasB;
  #pragma unroll
  for (int q = 0; q < 4; ++q) {
    biasA[q] = bih[layer * G4H + q * H_SZ + ecol] +
               bhh[layer * G4H + q * H_SZ + ecol];
    biasB[q] = bih[layer * G4H + q * H_SZ + ecol + 1] +
               bhh[layer * G4H + q * H_SZ + ecol + 1];
  }

  unsigned*       subflag   = bar + layer * 512 + cb * 4 + wave;  // wave<4
  const unsigned* chunk_own = bar + layer * 512 + wave * 64;      // 64 dwords
  const unsigned* chunk_l0  = bar + wave * 64;

  const unsigned short* ring_own = ringb + (size_t)layer * RING_SLOTS * HB;
  const unsigned short* ring_l0  = ringb;

  float cA = 0.f, cB = 0.f;
  float4_ acc[4][2];
  #pragma unroll
  for (int m = 0; m < 4; ++m)
    #pragma unroll
    for (int nt = 0; nt < 2; ++nt)
      acc[m][nt] = float4_{0.f, 0.f, 0.f, 0.f};

  // ---- prologue: x-side for t=0
  if (layer == 0) {
    accum_xp(acc, xp, wreg[0], nn, quad, wave);
  } else {
    wave_poll64(chunk_l0, 1u, lane);                  // h0(0) chunk ready
    accum_hb(acc, ring_l0 /*slot 0*/, wreg[0], nn, quad, wave);
  }

  #pragma unroll 1
  for (int t = 0; t < T_LEN; ++t) {
    // ---- per-wave wait: my chunk of h_own(t-1) ready (64 sub-flags)
    if (t > 0)
      wave_poll64(chunk_own, (unsigned)t, lane);

    // ---- recurrent half: h_own(t-1) at slot t-1 (t=0: slot T_LEN = h(-1))
    accum_hb(acc, ring_own + (size_t)(t ? t - 1 : T_LEN) * HB,
             wreg[1], nn, quad, wave);

    // ---- partials -> LDS[t&1], gate-permuted col = hcol*4 + gate
    float (*ldsb)[64][36] = lds[t & 1];
    #pragma unroll
    for (int m = 0; m < 4; ++m)
      #pragma unroll
      for (int nt = 0; nt < 2; ++nt)
        #pragma unroll
        for (int r = 0; r < 4; ++r)
          ldsb[wave][m * 16 + quad * 4 + r]
              [((nn & 7) << 2) + nt * 2 + (nn >> 3)] = acc[m][nt][r];
    __syncthreads();   // the ONLY barrier in the step

    if (wave < 4) {
      // ---- reduce over 8 K-waves + fused elementwise (16 batches/wave)
      float4_ gA = biasA, gB = biasB;
      #pragma unroll
      for (int w = 0; w < 8; ++w) {
        gA += *(const float4_*)&ldsb[w][eb][ec * 4];
        gB += *(const float4_*)&ldsb[w][eb][ec * 4 + 4];
      }
      float cpA, cpB;
      if (t == 0) {
        cpA = c0_in[(size_t)layer * HB + (size_t)eb * H_SZ + ecol];
        cpB = c0_in[(size_t)layer * HB + (size_t)eb * H_SZ + ecol + 1];
      } else { cpA = cA; cpB = cB; }
      const float igA = 1.f / (1.f + __expf(-gA[0]));
      const float fgA = 1.f / (1.f + __expf(-gA[1]));
      const float ggA = tanhf(gA[2]);
      const float ogA = 1.f / (1.f + __expf(-gA[3]));
      const float cnA = fgA * cpA + igA * ggA;
      const float hnA = ogA * tanhf(cnA);
      const float igB = 1.f / (1.f + __expf(-gB[0]));
      const float fgB = 1.f / (1.f + __expf(-gB[1]));
      const float ggB = tanhf(gB[2]);
      const float ogB = 1.f / (1.f + __expf(-gB[3]));
      const float cnB = fgB * cpB + igB * ggB;
      const float hnB = ogB * tanhf(cnB);
      cA = cnA; cB = cnB;
      const size_t ridx = ((size_t)layer * RING_SLOTS + t) * HB +
                          (size_t)eb * H_SZ + ecol;   // even -> 4B aligned
      const unsigned pk = (unsigned)bf16_rne(hnA) |
                          ((unsigned)bf16_rne(hnB) << 16);
      __hip_atomic_store((unsigned*)(ringb + ridx), pk,
                         __ATOMIC_RELAXED, __HIP_MEMORY_SCOPE_AGENT);
      if (layer == 1 && t == T_LEN - 1) {
        out[(size_t)eb * H_SZ + ecol]     = hnA;
        out[(size_t)eb * H_SZ + ecol + 1] = hnB;
      }
      // ---- per-wave drain + sub-flag (no barrier, no convoy)
      asm volatile("s_waitcnt vmcnt(0)" ::: "memory");
      if (lane == 0)
        __hip_atomic_store(subflag, (unsigned)(t + 1),
                           __ATOMIC_RELAXED, __HIP_MEMORY_SCOPE_AGENT);
    }

    // ---- shadow: x-side for t+1 (waves 4-7 start immediately post-barrier)
    if (t < T_LEN - 1) {
      #pragma unroll
      for (int m = 0; m < 4; ++m)
        #pragma unroll
        for (int nt = 0; nt < 2; ++nt)
          acc[m][nt] = float4_{0.f, 0.f, 0.f, 0.f};
      if (layer == 0) {
        accum_xp(acc, xp + (size_t)(t + 1) * HB, wreg[0], nn, quad, wave);
      } else {
        wave_poll64(chunk_l0, (unsigned)(t + 2), lane); // h0(t+1) chunk
        accum_hb(acc, ring_l0 + (size_t)(t + 1) * HB,
                 wreg[0], nn, quad, wave);
      }
    }
  }
}

extern "C" void kernel_launch(void* const* d_in, const int* in_sizes, int n_in,
                              void* d_out, int out_size, void* d_ws, size_t ws_size,
                              hipStream_t stream) {
  (void)in_sizes; (void)n_in; (void)out_size; (void)ws_size;
  const float* x   = (const float*)d_in[0];
  const float* h0  = (const float*)d_in[1];
  const float* c0  = (const float*)d_in[2];
  const float* Wih = (const float*)d_in[3];
  const float* Whh = (const float*)d_in[4];
  const float* bih = (const float*)d_in[5];
  const float* bhh = (const float*)d_in[6];
  float* out = (float*)d_out;

  // workspace (~134.5 MB): xpack 64 MB | bf16 ring 67.4 MB | bar 4 KB
  char* w = (char*)d_ws;
  unsigned*       xpack = (unsigned*)w;
  unsigned short* ringb = (unsigned short*)(w + (size_t)T_LEN * HB * 4);
  unsigned*       bar   = (unsigned*)(w + (size_t)T_LEN * HB * 4
                                        + (size_t)2 * RING_SLOTS * HB * 2);

  pack_x<<<(T_LEN * HB) / 4 / 256, 256, 0, stream>>>(x, xpack);
  init_h<<<2 * HB / 4 / 256, 256, 0, stream>>>(h0, ringb, bar);
  lstm_persist<<<NBLK, 512, 0, stream>>>(xpack, c0, Wih, Whh, bih, bhh,
                                         ringb, out, bar);
}